// Round 5
// baseline (547.935 us; speedup 1.0000x reference)
//
#include <hip/hip_runtime.h>
#include <hip/hip_bf16.h>

#define BATCH 16
#define NN 1024
#define MM 1024
#define DD 512

#define LOG2E 1.4426950408889634f
#define LN2f  0.6931471805599453f
#define NEGS  -1.442695e9f   // NEG (-1e9) scaled by log2e; acts as -inf sentinel

// nw_dp geometry: 16 blocks x 256 thr, 4 waves, 4 rows x 4 cols per lane per
// iteration. Critical path = 7 cells + 1 shuffle per 4 columns; all fixed
// per-iteration overhead (shuffle, loads, ring, fixups) amortized over 4 cols.
// Barrier every 16 iters; DSTAG = 252 + 4*17 = 320 so the producer->consumer
// ring gap is exactly 17 iterations (>= 1 barrier strictly between write and
// read). Ring = 256 slots x 4 cols = 1024 cols = exactly one lap: no WAR.
#define DSTAG 320
#define PF    4               // theta prefetch depth (iterations)
#define GTOT  560             // g_last = (1020 + 3*320 + 252)/4 = 558; mult of 16

typedef __bf16 v8bf __attribute__((ext_vector_type(8)));
typedef __bf16 v4bf __attribute__((ext_vector_type(4)));
typedef float  v4f  __attribute__((ext_vector_type(4)));

// ---------------------------------------------------------------- zero A acc
__global__ void zero_acc(float* a) {
    if (threadIdx.x < BATCH) a[threadIdx.x] = 0.0f;
}

// ------------------------------------------- fp32->bf16 convert + gap-dot
__global__ __launch_bounds__(256) void conv_reduce(
        const float* __restrict__ zx, const float* __restrict__ zy,
        const float* __restrict__ gw,
        __bf16* __restrict__ zxb, __bf16* __restrict__ zyb,
        float* __restrict__ acc) {
    const int chunk = blockIdx.x, b = blockIdx.y, which = blockIdx.z;
    const float* src = which ? zy : zx;
    __bf16* dst = which ? zyb : zxb;
    const float* g = gw + which * DD;
    const size_t base = ((size_t)b * NN + (size_t)chunk * 64) * DD;
    const int t = threadIdx.x;
    const int col = (t * 4) & (DD - 1);
    const float4 gv = *(const float4*)(g + col);
    float sum = 0.0f;
    #pragma unroll 4
    for (int it = 0; it < 32; ++it) {
        size_t off = base + (size_t)it * 1024 + t * 4;
        float4 x = *(const float4*)(src + off);
        sum += x.x * gv.x + x.y * gv.y + x.z * gv.z + x.w * gv.w;
        v4bf o = { (__bf16)x.x, (__bf16)x.y, (__bf16)x.z, (__bf16)x.w };
        *(v4bf*)(dst + off) = o;
    }
    #pragma unroll
    for (int o = 32; o > 0; o >>= 1) sum += __shfl_down(sum, o);
    __shared__ float wsum[4];
    if ((t & 63) == 0) wsum[t >> 6] = sum;
    __syncthreads();
    if (t == 0) {
        float s = wsum[0] + wsum[1] + wsum[2] + wsum[3];
        atomicAdd(acc + b, s * (1.0f / 1024.0f));
    }
}

// ------------------------------------------------------- bf16 MFMA NT GEMM
// m97-structure (guide §5 ladder step 3): 128x128 tile, 4 waves in 2x2,
// 4x4 16x16x32 MFMA frags per wave, BK=32, global_load_lds width 16,
// LINEAR LDS (required by global_load_lds; fragment ds_read_b128 of a wave
// covers a contiguous 1024B region -> conflict-free).
// out[row i][col j] = sum_d A[i,d]*B[j,d]. Called with A=zyb, B=zxb so the
// output buffer is thetaT[j_theta][i_theta] (theta transposed) at zero cost.
__global__ __launch_bounds__(256) void gemm_bt(
        const __bf16* __restrict__ Abf, const __bf16* __restrict__ Bbf,
        float* __restrict__ theta) {
    __shared__ __bf16 As[128 * 32];
    __shared__ __bf16 Bs[128 * 32];
    const int b = blockIdx.z;
    const int i0 = blockIdx.y * 128, j0 = blockIdx.x * 128;
    const __bf16* ap = Abf + ((size_t)b * NN + i0) * DD;
    const __bf16* bp = Bbf + ((size_t)b * MM + j0) * DD;
    const int t = threadIdx.x;
    const int lane = t & 63, wave = t >> 6;
    const int wr = wave >> 1, wc = wave & 1;       // 2x2 wave grid over the tile
    const int mrow = lane & 15, quad = lane >> 4;
    // staging map: wave v stages LDS bytes [v*2048, v*2048+2048) in 2 chunks of
    // 1024B (64 lanes x 16B). Lane l of chunk i covers row 32v+16i+(l>>2),
    // col elems (l&3)*8 .. +8 of the 128x32 tile.
    const int arow = wave * 32 + (lane >> 2);
    const int acol = (lane & 3) * 8;
    v4f acc[4][4] = {};
    for (int kk = 0; kk < DD; kk += 32) {
        __syncthreads();                           // protect LDS from prev reads
        #pragma unroll
        for (int i = 0; i < 2; ++i) {
            const __bf16* ga = ap + (size_t)(arow + 16 * i) * DD + kk + acol;
            const __bf16* gb = bp + (size_t)(arow + 16 * i) * DD + kk + acol;
            __builtin_amdgcn_global_load_lds(
                (const __attribute__((address_space(1))) void*)ga,
                (__attribute__((address_space(3))) void*)(As + wave * 1024 + i * 512),
                16, 0, 0);
            __builtin_amdgcn_global_load_lds(
                (const __attribute__((address_space(1))) void*)gb,
                (__attribute__((address_space(3))) void*)(Bs + wave * 1024 + i * 512),
                16, 0, 0);
        }
        __syncthreads();                           // compiler adds vmcnt(0) drain
        v8bf af[4];
        #pragma unroll
        for (int m = 0; m < 4; ++m)
            af[m] = *(const v8bf*)&As[(wr * 64 + m * 16 + mrow) * 32 + quad * 8];
        #pragma unroll
        for (int n = 0; n < 4; ++n) {
            v8bf bf = *(const v8bf*)&Bs[(wc * 64 + n * 16 + mrow) * 32 + quad * 8];
            #pragma unroll
            for (int m = 0; m < 4; ++m)
                acc[m][n] = __builtin_amdgcn_mfma_f32_16x16x32_bf16(af[m], bf, acc[m][n], 0, 0, 0);
        }
    }
    const size_t tb = (size_t)b * NN * MM;
    #pragma unroll
    for (int n = 0; n < 4; ++n) {
        int j = j0 + wc * 64 + n * 16 + mrow;
        #pragma unroll
        for (int m = 0; m < 4; ++m) {
            #pragma unroll
            for (int r = 0; r < 4; ++r) {
                int i = i0 + wr * 64 + m * 16 + quad * 4 + r;
                theta[tb + (size_t)i * MM + j] = acc[m][n][r];
            }
        }
    }
}

// --------------------------------------------------- soft-NW wavefront DP
// 4 waves per batch (256 threads). Wave w owns V-rows 256w+1..256w+256, lane
// owns 4 rows and processes a 4x4 tile (cols C..C+3) per iteration.
// Inputs per iter: ta..td = V[row0-1][C..C+3] (shuffles of neighbor's saved
// bottom values / ring for lane 0), tp = V[row0-1][C-1] (= prev iter's td).
// Chain cuts (proven absmax-0 in rounds 1-3):
//  - "1+" lse3: ss = 1 + exp2(med-mx) + exp2(mn-mx) via max3/med3/min3
//  - c1 folding: c1 = fma(th,log2e,mx) off-chain; uu = l + (c1+Ac)
__global__ __launch_bounds__(256) void nw_dp(
        const float* __restrict__ thetaT, const float* __restrict__ acc,
        const float* __restrict__ gap_b, float* __restrict__ out) {
    const int b = blockIdx.x;
    const int tid = threadIdx.x;
    const int t = tid & 63, w = tid >> 6;
    const float Ac = (acc[b] + gap_b[0]) * LOG2E;
    const int row0 = w * 256 + t * 4;          // theta rows row0..row0+3
    const int off4 = w * DSTAG + 4 * t;        // lane's column lag (cols)
    const float* Tb = thetaT + (size_t)b * NN * MM + row0;

    __shared__ float4 ring[3][256];            // 256 slots x 4 cols = full lap

    float v0 = NEGS, v1 = NEGS, v2 = NEGS, v3 = NEGS;
    float s0 = NEGS, s1 = NEGS, s2 = NEGS, s3 = NEGS; // bottom vals @ C..C+3 (prev iter)
    float tpp = NEGS;                          // prev iteration's td
    float4 rt; rt.x = NEGS; rt.y = NEGS; rt.z = NEGS; rt.w = NEGS;

    float4 pf[PF][4];
    #pragma unroll
    for (int u = 0; u < PF; ++u) {
        int cn = 4 * u - off4;                 // <= 12: low clamp only
        cn = cn < 0 ? 0 : cn;
        #pragma unroll
        for (int k = 0; k < 4; ++k)
            pf[u][k] = *(const float4*)(Tb + (size_t)(cn + k) * NN);
    }

    // one cell: updates vk (row value), uu (next row's up+Ac), dg (next diag)
    #define CELL(vk, th) {                                                   \
        float lf = vk + Ac;                                                  \
        float mx = fmaxf(fmaxf(uu, dg), lf);                                 \
        float md = __builtin_amdgcn_fmed3f(uu, dg, lf);                      \
        float mn = fminf(fminf(uu, dg), lf);                                 \
        float ss = 1.0f + __builtin_amdgcn_exp2f(md - mx)                    \
                        + __builtin_amdgcn_exp2f(mn - mx);                   \
        float l  = __builtin_amdgcn_logf(ss);                                \
        float c1 = fmaf(th, LOG2E, mx);                                      \
        dg = vk;                                                             \
        vk = l + c1;                                                         \
        uu = l + (c1 + Ac);                                                  \
    }

    for (int gg = 0; gg < GTOT; gg += PF) {
        #pragma unroll
        for (int u = 0; u < PF; ++u) {
            const int g = gg + u;
            const int C = 4 * g - off4;        // multiple of 4; C valid => C+3 valid

            float ta = __shfl_up(s0, 1);       // V[row0-1][C]
            float tb_ = __shfl_up(s1, 1);      // V[row0-1][C+1]
            float tc = __shfl_up(s2, 1);       // V[row0-1][C+2]
            float td = __shfl_up(s3, 1);       // V[row0-1][C+3]
            if (t == 0) {
                if (w == 0) { ta = NEGS; tb_ = NEGS; tc = NEGS; td = NEGS; }
                else        { ta = rt.x; tb_ = rt.y; tc = rt.z; td = rt.w; }
            }
            float tp = tpp;                    // V[row0-1][C-1]
            if (t == 0 && C == 0) tp = (w == 0) ? 0.0f : NEGS;
            tpp = td;

            const float4 cA = pf[u][0], cB = pf[u][1], cC = pf[u][2], cD = pf[u][3];
            // re-issue this slot: columns for iteration g + PF
            int cn = 4 * (g + PF) - off4;
            cn = cn < 0 ? 0 : (cn > MM - 4 ? MM - 4 : cn);
            #pragma unroll
            for (int k = 0; k < 4; ++k)
                pf[u][k] = *(const float4*)(Tb + (size_t)(cn + k) * NN);

            if ((unsigned)C < MM) {
                float uu, dg;
                // column C
                uu = ta + Ac; dg = tp;
                CELL(v0, cA.x) CELL(v1, cA.y) CELL(v2, cA.z) CELL(v3, cA.w)
                s0 = v3;
                // column C+1 (top diag = V[row0-1][C] = ta)
                uu = tb_ + Ac; dg = ta;
                CELL(v0, cB.x) CELL(v1, cB.y) CELL(v2, cB.z) CELL(v3, cB.w)
                s1 = v3;
                // column C+2
                uu = tc + Ac; dg = tb_;
                CELL(v0, cC.x) CELL(v1, cC.y) CELL(v2, cC.z) CELL(v3, cC.w)
                s2 = v3;
                // column C+3
                uu = td + Ac; dg = tc;
                CELL(v0, cD.x) CELL(v1, cD.y) CELL(v2, cD.z) CELL(v3, cD.w)
                s3 = v3;
                if (t == 63 && w < 3) {
                    float4 pr; pr.x = s0; pr.y = s1; pr.z = s2; pr.w = s3;
                    ring[w][(C >> 2) & 255] = pr;
                }
            }

            if ((g & 15) == 15) __syncthreads();

            // ring prefetch for iteration g+1 (producer wrote these columns 17
            // iterations earlier; >=1 barrier strictly between; ring is exactly
            // one lap per batch so no WAR hazard).
            if (t == 0 && w > 0) {
                int c0n = 4 * (g + 1) - w * DSTAG;   // lane 0's next col C
                rt = ring[w - 1][(c0n >> 2) & 255];
            }
        }
    }
    #undef CELL
    if (tid == 255) out[b] = v3 * LN2f;
}

// ---------------------------------------------------------------- launcher
extern "C" void kernel_launch(void* const* d_in, const int* in_sizes, int n_in,
                              void* d_out, int out_size, void* d_ws, size_t ws_size,
                              hipStream_t stream) {
    const float* zx    = (const float*)d_in[0];
    const float* zy    = (const float*)d_in[1];
    const float* gw    = (const float*)d_in[2];
    const float* gapb  = (const float*)d_in[3];
    float* out = (float*)d_out;

    char* ws = (char*)d_ws;
    float*  thetaT = (float*)ws;                                  // 67,108,864 B
    __bf16* zxb   = (__bf16*)(ws + (size_t)67108864);             // 16,777,216 B
    __bf16* zyb   = (__bf16*)(ws + (size_t)67108864 + 16777216);  // 16,777,216 B
    float*  acc   = (float*)(ws + (size_t)67108864 + 2 * 16777216);

    zero_acc<<<1, 64, 0, stream>>>(acc);
    conv_reduce<<<dim3(16, BATCH, 2), 256, 0, stream>>>(zx, zy, gw, zxb, zyb, acc);
    // swapped args: output = theta^T
    gemm_bt<<<dim3(MM / 128, NN / 128, BATCH), 256, 0, stream>>>(zyb, zxb, thetaT);
    nw_dp<<<BATCH, 256, 0, stream>>>(thetaT, acc, gapb, out);
}